// Round 8
// baseline (59.382 us; speedup 1.0000x reference)
//
#include <hip/hip_runtime.h>

#define NATOMS 512
#define N2 (NATOMS*NATOMS)
#define NPOLY 12
#define NSP 4
#define NSMAX 96            // K padded to 3 x 32 (81 real + 15 sentinels)
#define TJ 64
#define NTHREADS 256

typedef __attribute__((ext_vector_type(8))) short bf16x8;
typedef __attribute__((ext_vector_type(4))) float f32x4;

static __device__ __forceinline__ unsigned f2bf2(float lo, float hi) {
    union { float f; unsigned u; } a, b; a.f = lo; b.f = hi;
    unsigned ra = a.u + 0x7FFFu + ((a.u >> 16) & 1u);   // RNE bf16
    unsigned rb = b.u + 0x7FFFu + ((b.u >> 16) & 1u);
    return (ra >> 16) | (rb & 0xFFFF0000u);
}

// eval-chunk permutation: rank R (distance order) -> table position
// position p = kf*32 + g*8 + e2*2 + h must hold rank kf*32 + (e2*2+h)*4 + g,
// so each (kf,e2) ballot chunk covers 8 rank-consecutive shifts.
static __device__ __forceinline__ int rank2pos(int R) {
    int kf = R >> 5, rr = R & 31, chunk = rr >> 2, g = rr & 3;
    return kf*32 + g*8 + (chunk >> 1)*2 + (chunk & 1);
}

// ---- kernel 0: permute shifts to eval-chunk near-first order, sentinels ----
__global__ void prep_shifts(const float* __restrict__ shifts,
                            float4* __restrict__ shp4, int ns)
{
    __shared__ unsigned char big[NSMAX];
    int t = threadIdx.x;                  // 128 threads
    bool isbig = false;
    float x = 0.f, y = 0.f, z = 0.f;
    if (t < ns) {
        x = shifts[t*3]; y = shifts[t*3+1]; z = shifts[t*3+2];
        isbig = (fabsf(x) > 7.5f) || (fabsf(y) > 7.5f) || (fabsf(z) > 7.5f);
    }
    if (t < NSMAX) big[t] = (t < ns && isbig) ? 1 : 0;
    __syncthreads();
    if (t < NSMAX) {
        int rankpos;
        if (t < ns) {
            int nnear = 0, rank = 0;
            unsigned char me = isbig ? 1 : 0;
            for (int s = 0; s < ns; ++s) {
                nnear += (big[s] == 0);
                rank  += (s < t) && (big[s] == me);
            }
            rankpos = isbig ? (nnear + rank) : rank;
        } else {
            rankpos = t;                  // sentinel ranks ns..95
        }
        int pos = rank2pos(rankpos);
        shp4[pos] = (t < ns) ? make_float4(x, y, z, 0.f)
                             : make_float4(1e9f, 1e9f, 1e9f, 0.f);
    }
}

// ---- kernel 1: phase table Ttg[64][96] bf16 (permuted s order) ----
// rows 0..31: cos(2*pi*(kpt[k]/5).shift[s]); rows 32..63: sin; 0 at sentinels.
__global__ void phase_tab(const float* __restrict__ kpoints,
                          const float4* __restrict__ shp4,
                          unsigned* __restrict__ Ttg)
{
    int idx = blockIdx.x * 256 + threadIdx.x;        // 64*48 = 3072 dwords
    if (idx >= 64 * 48) return;
    int row = idx / 48, s2 = idx - row * 48;
    int k = row & 31;
    float kcx = kpoints[k*3]   * 0.2f;
    float kcy = kpoints[k*3+1] * 0.2f;
    float kcz = kpoints[k*3+2] * 0.2f;
    float val[2] = {0.f, 0.f};
    #pragma unroll
    for (int h = 0; h < 2; ++h) {
        float4 sh = shp4[2*s2 + h];
        if (sh.x < 1e8f) {
            float d = (kcx*sh.x + kcy*sh.y) + kcz*sh.z;
            float sn, cs;
            sincosf(6.283185307179586f * d, &sn, &cs);
            val[h] = (row >= 32) ? sn : cs;
        }
    }
    Ttg[idx] = f2bf2(val[0], val[1]);
}

// ---- kernel 2: main (no V-LDS, no phase barriers, register A-frags) ----
__global__ __launch_bounds__(NTHREADS, 4)
void dftb8(const float* __restrict__ positions,
           const int* __restrict__ species,
           const float* __restrict__ param,
           const float* __restrict__ onsite,
           const float4* __restrict__ shp4,
           const unsigned short* __restrict__ Ttg,
           float* __restrict__ out)
{
    __shared__ float4 sh4p[NSMAX + NSMAX/8];  // padded (s + s/8): g-groups 4 banks apart

    const int tid = threadIdx.x;
    const int bi = blockIdx.x >> 3;           // i row
    const int jt = blockIdx.x & 7;            // j octant
    const int si = species[bi];

    if (tid < NSMAX) {
        int s = tid;
        sh4p[s + (s >> 3)] = shp4[s];
    }
    __syncthreads();                          // the only barrier

    const int lane = tid & 63, w = tid >> 6;
    const int r16 = lane & 15, g = lane >> 4;

    const float pix = positions[bi*3], piy = positions[bi*3+1], piz = positions[bi*3+2];
    const float ons = onsite[si];

    // this lane's pair: j = jt*64 + w*16 + r16 (A-row r16); g = s-slice
    const int j = jt*TJ + w*16 + r16;
    const float pjx = positions[j*3], pjy = positions[j*3+1], pjz = positions[j*3+2];
    const int sj = species[j];
    float c[NPOLY];
    #pragma unroll
    for (int q = 0; q < NPOLY; ++q) c[q] = param[(si*NSP + sj)*NPOLY + q];

    // ---- phase A: A-frags in registers; ballot skips far/sentinel chunks ----
    bf16x8 A[3];
    #pragma unroll
    for (int kf = 0; kf < 3; ++kf) {
        unsigned pk[4];
        #pragma unroll
        for (int e2 = 0; e2 < 4; ++e2) {
            const int s0 = kf*32 + g*8 + e2*2;
            float4 sa = sh4p[s0 + (s0 >> 3)];
            const int s1 = s0 + 1;
            float4 sb = sh4p[s1 + (s1 >> 3)];
            // numpy order: (pj + shift) - pi ; (x^2+y^2)+z^2, no FMA contraction
            float dxa = (pjx + sa.x) - pix, dya = (pjy + sa.y) - piy, dza = (pjz + sa.z) - piz;
            float dxb = (pjx + sb.x) - pix, dyb = (pjy + sb.y) - piy, dzb = (pjz + sb.z) - piz;
            float dr2a = (__fmul_rn(dxa,dxa) + __fmul_rn(dya,dya)) + __fmul_rn(dza,dza);
            float dr2b = (__fmul_rn(dxb,dxb) + __fmul_rn(dyb,dyb)) + __fmul_rn(dzb,dzb);
            float va = 0.f, vb = 0.f;
            bool m = (dr2a <= 36.001f) || (dr2b <= 36.001f);
            if (__ballot(m) != 0ULL) {        // rank-contiguous chunk skip
                float dra = sqrtf(dr2a);      // correctly-rounded fp32
                float drb = sqrtf(dr2b);
                if (dra > 0.1f && dra <= 6.0f) {     // exact gate
                    float x = dra * 1.8897261258369282f;
                    float y = c[NPOLY-1];
                    #pragma unroll
                    for (int q = NPOLY-2; q >= 0; --q) y = fmaf(y, x, c[q]);
                    va = y;
                }
                if (drb > 0.1f && drb <= 6.0f) {
                    float x = drb * 1.8897261258369282f;
                    float y = c[NPOLY-1];
                    #pragma unroll
                    for (int q = NPOLY-2; q >= 0; --q) y = fmaf(y, x, c[q]);
                    vb = y;
                }
            }
            pk[e2] = f2bf2(va, vb);
        }
        union { unsigned u[4]; bf16x8 v; } au;
        au.u[0] = pk[0]; au.u[1] = pk[1]; au.u[2] = pk[2]; au.u[3] = pk[3];
        A[kf] = au.v;
    }

    // ---- phase B: all B-frags up front (12 outstanding loads), MFMA, store ----
    bf16x8 B[4][3];
    #pragma unroll
    for (int nf = 0; nf < 4; ++nf) {
        const unsigned short* tb = Ttg + (size_t)(nf*16 + r16)*NSMAX + g*8;
        B[nf][0] = *(const bf16x8*)(tb);
        B[nf][1] = *(const bf16x8*)(tb + 32);
        B[nf][2] = *(const bf16x8*)(tb + 64);
    }

    const int jb = jt*TJ + w*16 + g*4;
    const int dons = bi - jb;                 // onsite reg index if 0..3
    float* obase = out + (size_t)r16*N2 + (size_t)bi*NATOMS + jb;

    #pragma unroll
    for (int nf = 0; nf < 4; ++nf) {
        f32x4 acc = {0.f, 0.f, 0.f, 0.f};
        acc = __builtin_amdgcn_mfma_f32_16x16x32_bf16(A[0], B[nf][0], acc, 0, 0, 0);
        acc = __builtin_amdgcn_mfma_f32_16x16x32_bf16(A[1], B[nf][1], acc, 0, 0, 0);
        acc = __builtin_amdgcn_mfma_f32_16x16x32_bf16(A[2], B[nf][2], acc, 0, 0, 0);
        // C/D layout: col(lane&15)=kcol-in-16, row(g*4+reg)=pair-in-16
        float4 v; v.x = acc[0]; v.y = acc[1]; v.z = acc[2]; v.w = acc[3];
        if (nf < 2 && dons >= 0 && dons < 4)  // kcol<32 -> Hr plane: onsite diag
            ((float*)&v)[dons] += ons;
        *(float4*)(obase + (size_t)(nf*16)*N2) = v;
    }
}

extern "C" void kernel_launch(void* const* d_in, const int* in_sizes, int n_in,
                              void* d_out, int out_size, void* d_ws, size_t ws_size,
                              hipStream_t stream) {
    const float* positions = (const float*)d_in[0];
    const int*   species   = (const int*)d_in[1];
    const float* kpoints   = (const float*)d_in[2];
    const float* param     = (const float*)d_in[3];
    const float* onsite    = (const float*)d_in[4];
    const float* shifts    = (const float*)d_in[5];
    int ns = in_sizes[5] / 3;
    float* out = (float*)d_out;

    float4*   shp4 = (float4*)d_ws;                       // 96*16 = 1536 B
    unsigned* Ttg  = (unsigned*)((char*)d_ws + 2048);     // 64*96*2 = 12 KB

    prep_shifts<<<dim3(1), 128, 0, stream>>>(shifts, shp4, ns);
    phase_tab<<<dim3(12), 256, 0, stream>>>(kpoints, shp4, Ttg);
    dim3 grid(NATOMS * (NATOMS/TJ));                      // 512 * 8 = 4096 blocks
    dftb8<<<grid, NTHREADS, 0, stream>>>(positions, species, param, onsite,
                                         shp4, (const unsigned short*)Ttg, out);
}